// Round 10
// baseline (88.303 us; speedup 1.0000x reference)
//
#include <hip/hip_runtime.h>
#include <math.h>

// Tropical (max-plus) matmul: y[b,o] = max_i (x[b,i] + W[o,i])
// x: [512,1024] f32, W: [1024,1024] f32 (K-innermost), y: [512,1024] f32.
//
// Round-10: kill the ~29us staging constant.
//   Session evidence: partial is pinned at ~37-51us across 2/1.5/1 B/op LDS
//   structures; r5's counters show ~3x VALU-inst bloat vs hand count ->
//   the cost is reg->LDS staging glue + v2f repack codegen, not pipe capacity.
//   Fix: global_load_lds (width=16) straight into LINEAR k-major LDS:
//     - pre-transpose x -> xT[1024][512], W -> wT[1024][1024] (one cheap
//       32x33-LDS transpose kernel, ~3us for 6 MB);
//     - per K-tile (BK=16): 4+2 global_load_lds insts fill As[16][64],
//       Bs[16][32]; ZERO staging VGPRs, ZERO ds_writes, ZERO repack;
//     - lane tile 8x4 (1.5 B/op); K consumed 2 at a time with
//       acc = fmax(fmax(acc, a0+b0), a1+b1) -> v_max3 fold, 1.5 inst/elem,
//       no register-pairing constraints for the compiler to mangle;
//     - 64-thr wave-blocks (barriers ~free), VGPR ~75, LDS 6.1 KB ->
//       KS=16, 4096 blocks = 16/CU = 4 waves/SIMD.
// Split-K: 256 tiles x KS=16 -> part (32 MB) -> 16-deep reduce (proven ~6us).

#define MDIM 512
#define NDIM 1024
#define KDIM 1024

#define BK   16
#define WTM  64            // wave tile m
#define WTN  32            // wave tile n
#define KS   16
#define NTHREADS 64

// global_load_lds: per-lane global src, wave-uniform LDS base; HW writes
// lds_base + lane*16B. Size must be a literal 16.
#define GLOAD16(gsrc, ldst)                                              \
    __builtin_amdgcn_global_load_lds(                                    \
        (const __attribute__((address_space(1))) unsigned int*)(gsrc),   \
        (__attribute__((address_space(3))) unsigned int*)(ldst), 16, 0, 0)

// 32x32-tile float transpose: in[R][C] -> out[C][R]
__global__ __launch_bounds__(256)
void transpose_f32(const float* __restrict__ in, float* __restrict__ out,
                   int R, int C) {
    __shared__ float t[32][33];
    const int tx = threadIdx.x & 31, ty = threadIdx.x >> 5;   // 32x8
    const int c0 = blockIdx.x * 32, r0 = blockIdx.y * 32;
#pragma unroll
    for (int j = 0; j < 4; ++j)
        t[ty + 8 * j][tx] = in[(size_t)(r0 + ty + 8 * j) * C + c0 + tx];
    __syncthreads();
#pragma unroll
    for (int j = 0; j < 4; ++j)
        out[(size_t)(c0 + ty + 8 * j) * R + r0 + tx] = t[tx][ty + 8 * j];
}

// partial: one 64-thr wave per 64x32 output tile per K-slice.
__global__ __launch_bounds__(NTHREADS, 4)
void tropical_partial(const float* __restrict__ xT,   // [KDIM][MDIM]
                      const float* __restrict__ wT,   // [KDIM][NDIM]
                      float* __restrict__ part, int KC) {
    __shared__ float As[BK * WTM];   // [k][m], 4096 B, linear
    __shared__ float Bs[BK * WTN];   // [k][n], 2048 B, linear

    const int tiles_n = NDIM / WTN;                 // 32
    const int tm0 = (blockIdx.x / tiles_n) * WTM;
    const int tn0 = (blockIdx.x % tiles_n) * WTN;
    const int k0  = blockIdx.y * KC;

    const int l  = threadIdx.x;
    const int tx = l & 7;            // n-direction (4 cols each)
    const int ty = l >> 3;           // m-direction (8 rows each)

    float acc[8][4];
#pragma unroll
    for (int i = 0; i < 8; ++i)
#pragma unroll
        for (int j = 0; j < 4; ++j) acc[i][j] = -INFINITY;

    // per-lane global sources for the load_lds mapping (LDS off = 256j + 4l)
    // A inst j: row kb + 4j + (l>>4), col m0 + (l&15)*4
    const float* ga = xT + (size_t)(k0 + (l >> 4)) * MDIM + tm0 + (l & 15) * 4;
    // B inst j: row kb + 8j + (l>>3), col n0 + (l&7)*4
    const float* gb = wT + (size_t)(k0 + (l >> 3)) * NDIM + tn0 + (l & 7) * 4;

    const int nt = KC / BK;
    for (int t = 0; t < nt; ++t) {
        // issue the 6 direct global->LDS loads for tile t
        const float* gat = ga + (size_t)t * BK * MDIM;
        const float* gbt = gb + (size_t)t * BK * NDIM;
        GLOAD16(gat,                       &As[0]);
        GLOAD16(gat + (size_t)4  * MDIM,   &As[256]);
        GLOAD16(gat + (size_t)8  * MDIM,   &As[512]);
        GLOAD16(gat + (size_t)12 * MDIM,   &As[768]);
        GLOAD16(gbt,                       &Bs[0]);
        GLOAD16(gbt + (size_t)8  * NDIM,   &Bs[256]);
        __syncthreads();   // drains vmcnt(0): LDS tile ready

        // compute: 8 k-pairs; per pair 6x ds_read_b128 + 96 VALU (add,add,max3)
#pragma unroll
        for (int kk = 0; kk < BK; kk += 2) {
            const float* ra = As + kk * WTM + 8 * ty;
            const float* rb = Bs + kk * WTN + 4 * tx;
            const float4 a00 = *(const float4*)(ra);
            const float4 a01 = *(const float4*)(ra + 4);
            const float4 a10 = *(const float4*)(ra + WTM);
            const float4 a11 = *(const float4*)(ra + WTM + 4);
            const float4 b0  = *(const float4*)(rb);
            const float4 b1  = *(const float4*)(rb + WTN);
            const float a0f[8] = {a00.x, a00.y, a00.z, a00.w,
                                  a01.x, a01.y, a01.z, a01.w};
            const float a1f[8] = {a10.x, a10.y, a10.z, a10.w,
                                  a11.x, a11.y, a11.z, a11.w};
            const float b0f[4] = {b0.x, b0.y, b0.z, b0.w};
            const float b1f[4] = {b1.x, b1.y, b1.z, b1.w};
#pragma unroll
            for (int i = 0; i < 8; ++i)
#pragma unroll
                for (int j = 0; j < 4; ++j)
                    acc[i][j] = fmaxf(fmaxf(acc[i][j], a0f[i] + b0f[j]),
                                      a1f[i] + b1f[j]);      // v_max3_f32
        }
        __syncthreads();   // all frag reads done before next tile's loads land
    }

    // epilogue: lane owns rows tm0+8ty+i, cols tn0+4tx..+3 (float4 stores)
    float* dst = part + (size_t)blockIdx.y * (MDIM * NDIM);
#pragma unroll
    for (int i = 0; i < 8; ++i) {
        *(float4*)&dst[(size_t)(tm0 + 8 * ty + i) * NDIM + tn0 + 4 * tx] =
            make_float4(acc[i][0], acc[i][1], acc[i][2], acc[i][3]);
    }
}

__global__ __launch_bounds__(256)
void tropical_reduce(const float* __restrict__ ws, float* __restrict__ out,
                     int ks) {
    const int i = blockIdx.x * 256 + threadIdx.x;    // float4 index (exact grid)
    const int stride = MDIM * NDIM / 4;
    const float4* w4 = (const float4*)ws;
    float4 m = w4[i];
#pragma unroll 8
    for (int s = 1; s < ks; ++s) {
        const float4 v = w4[(size_t)s * stride + i];
        m.x = fmaxf(m.x, v.x); m.y = fmaxf(m.y, v.y);
        m.z = fmaxf(m.z, v.z); m.w = fmaxf(m.w, v.w);
    }
    ((float4*)out)[i] = m;
}

// correctness-only fallback if workspace is too small
__global__ __launch_bounds__(256)
void tropical_naive(const float* __restrict__ x, const float* __restrict__ W,
                    float* __restrict__ out) {
    const int idx = blockIdx.x * 256 + threadIdx.x;
    const int b = idx >> 10, n = idx & 1023;
    const float4* xr = (const float4*)(x + (size_t)b * KDIM);
    const float4* wr = (const float4*)(W + (size_t)n * KDIM);
    float m = -INFINITY;
    for (int k = 0; k < KDIM / 4; ++k) {
        const float4 a = xr[k], w = wr[k];
        m = fmaxf(m, fmaxf(fmaxf(a.x + w.x, a.y + w.y),
                           fmaxf(a.z + w.z, a.w + w.w)));
    }
    out[idx] = m;
}

extern "C" void kernel_launch(void* const* d_in, const int* in_sizes, int n_in,
                              void* d_out, int out_size, void* d_ws, size_t ws_size,
                              hipStream_t stream) {
    const float* x = (const float*)d_in[0];
    const float* W = (const float*)d_in[1];
    float* out = (float*)d_out;

    const size_t xTsz  = (size_t)KDIM * MDIM * sizeof(float);   // 2 MB
    const size_t wTsz  = (size_t)KDIM * NDIM * sizeof(float);   // 4 MB
    const size_t slice = (size_t)MDIM * NDIM * sizeof(float);   // 2 MB
    const size_t need  = xTsz + wTsz + (size_t)KS * slice;      // 38 MB

    if (need > ws_size) {
        tropical_naive<<<MDIM * NDIM / 256, 256, 0, stream>>>(x, W, out);
        return;
    }

    float* xT   = (float*)d_ws;
    float* wT   = (float*)((char*)d_ws + xTsz);
    float* part = (float*)((char*)d_ws + xTsz + wTsz);

    // x [512][1024] -> xT [1024][512];  W [1024][1024] -> wT [1024][1024]
    transpose_f32<<<dim3(KDIM / 32, MDIM / 32), 256, 0, stream>>>(x, xT, MDIM, KDIM);
    transpose_f32<<<dim3(KDIM / 32, NDIM / 32), 256, 0, stream>>>(W, wT, NDIM, KDIM);

    const int ntiles = (MDIM / WTM) * (NDIM / WTN);   // 256
    const int KC = KDIM / KS;                         // 64
    tropical_partial<<<dim3(ntiles, KS), NTHREADS, 0, stream>>>(xT, wT, part, KC);

    tropical_reduce<<<MDIM * NDIM / 4 / 256, 256, 0, stream>>>(part, out, KS);
}